// Round 9
// baseline (142.921 us; speedup 1.0000x reference)
//
#include <hip/hip_runtime.h>
#include <hip/hip_bf16.h>

// Problem constants (B=4096, D=1024 per reference setup_inputs)
#define B_ROWS 4096
#define D_DIM  1024          // elements == bytes in fp8
#define N_ROWS 8192          // 2B
// values scaled by 16 before fp8 cast -> sim scaled by 256; exp arg factor:
#define EXP_SCALE 0.0078125f // TEMP_INV / 256 = 2/256
#define FP8_SCALE 16.0f

#define NTILE 64
#define GRID_SIM 2080        // upper-triangle tiles incl. diagonal

typedef __attribute__((ext_vector_type(4))) float f32x4;   // MFMA C/D frag
typedef __attribute__((ext_vector_type(8))) int   i32x8;   // MX MFMA A/B frag

// Async global->LDS DMA, 16 B per lane. LDS dest is WAVE-UNIFORM base;
// lane i's 16 B land at base + i*16 (per-lane global addr is free-form).
__device__ inline void load_lds16(const unsigned char* g, unsigned char* l) {
    __builtin_amdgcn_global_load_lds(
        (const __attribute__((address_space(1))) unsigned int*)g,
        (__attribute__((address_space(3))) unsigned int*)l,
        16, 0, 0);
}

// ---------------------------------------------------------------------------
// Kernel 1 (R13 form): block-per-row L2 normalize -> fp8 e4m3 reps (x16
// scale), [8192] rows x 1024 B. 4096 blocks x 256 thr; thread t owns
// elements 4t..4t+3 of row b in BOTH emb_i and emb_j. Coalesced 16 B/lane
// loads, butterfly + LDS cross-wave reduce, 4 B/lane fp8 stores.
// pos[b] = z_i(b).z_j(b) in fp32 (exact). Zeroes denom + ticket counter.
// (R16's 4-row variant was neutral — keep the simpler form.)
// ---------------------------------------------------------------------------
__global__ __launch_bounds__(256)
void normalize_kernel(const float* __restrict__ emb_i,
                      const float* __restrict__ emb_j,
                      unsigned char* __restrict__ reps,
                      float* __restrict__ pos,
                      float* __restrict__ denom,
                      int* __restrict__ counter) {
    const int b    = blockIdx.x;                     // 0..4095 (one row pair)
    const int t    = threadIdx.x;                    // 0..255
    const int lane = t & 63;
    const int wave = t >> 6;

    if (b < N_ROWS / 256) denom[b * 256 + t] = 0.0f;
    if (b == 0 && t == 0)
        __hip_atomic_store(counter, 0, __ATOMIC_RELAXED,
                           __HIP_MEMORY_SCOPE_AGENT);   // ticket reset

    const float4 vi = ((const float4*)(emb_i + (size_t)b * D_DIM))[t];
    const float4 vj = ((const float4*)(emb_j + (size_t)b * D_DIM))[t];

    float si = vi.x*vi.x + vi.y*vi.y + vi.z*vi.z + vi.w*vi.w;
    float sj = vj.x*vj.x + vj.y*vj.y + vj.z*vj.z + vj.w*vj.w;
    float sd = vi.x*vj.x + vi.y*vj.y + vi.z*vj.z + vi.w*vj.w;

    #pragma unroll
    for (int off = 32; off >= 1; off >>= 1) {   // butterfly within wave
        si += __shfl_xor(si, off);
        sj += __shfl_xor(sj, off);
        sd += __shfl_xor(sd, off);
    }
    __shared__ float red[3][4];
    if (lane == 0) { red[0][wave] = si; red[1][wave] = sj; red[2][wave] = sd; }
    __syncthreads();
    si = red[0][0] + red[0][1] + red[0][2] + red[0][3];
    sj = red[1][0] + red[1][1] + red[1][2] + red[1][3];
    sd = red[2][0] + red[2][1] + red[2][2] + red[2][3];

    const float inv_i = FP8_SCALE / fmaxf(sqrtf(si), 1e-12f);
    const float inv_j = FP8_SCALE / fmaxf(sqrtf(sj), 1e-12f);
    if (t == 0) pos[b] = sd * (inv_i * inv_j) * (1.0f / (FP8_SCALE * FP8_SCALE));

    int a  = __builtin_amdgcn_cvt_pk_fp8_f32(vi.x * inv_i, vi.y * inv_i, 0, false);
    unsigned int ui = __builtin_amdgcn_cvt_pk_fp8_f32(vi.z * inv_i, vi.w * inv_i, a, true);
    int c  = __builtin_amdgcn_cvt_pk_fp8_f32(vj.x * inv_j, vj.y * inv_j, 0, false);
    unsigned int uj = __builtin_amdgcn_cvt_pk_fp8_f32(vj.z * inv_j, vj.w * inv_j, c, true);

    ((unsigned int*)(reps + (size_t)b * D_DIM))[t]            = ui;
    ((unsigned int*)(reps + (size_t)(b + B_ROWS) * D_DIM))[t] = uj;
}

// ---------------------------------------------------------------------------
// Kernel 2 (R17): EXACT R8/R13 K-loop (57.5 us fingerprint, (256,3),
// VGPR 84 + 64 AGPR acc). Added: FENCE-FREE fused-loss ticket tail.
//
// R15 postmortem: __threadfence() (device-scope fence -> L2 writeback/inv)
// executed by ALL 2080 blocks poisoned reps' L2/L3 residency (57.5->236us).
// The fence is unnecessary: denom atomicAdds are device-coherent already
// (global atomics execute at the coherent point, m20). Required ordering is
// only ISSUE order -> raw s_waitcnt vmcnt(0), zero cache maintenance.
// Ticket RMW is RELAXED/AGENT (no implicit flush, unlike ACQ_REL); last
// block reads denom via RELAXED/AGENT atomic loads (per-access coherent
// bits, no global invalidate).
//
// RETIRED LEVERS: deeper pipelines (R9-R12), occupancy 4/CU (R14 spill),
// threadfence fusion (R15). Do not restructure the K-loop.
// ---------------------------------------------------------------------------
#define BM 128
#define BKB 128              // K-bytes (== elements) staged per iter

__global__ __launch_bounds__(256, 3)
void sim_denom_kernel(const unsigned char* __restrict__ reps,
                      float* __restrict__ denom,
                      const float* __restrict__ pos,
                      float* __restrict__ out,
                      int* __restrict__ counter) {
    // ---- tile decode: bid -> (rt, ct), rt <= ct (grouped enumeration) ----
    const int bid = blockIdx.x;
    int g = (int)((__builtin_sqrtf(1.0f + 8.0f * (float)bid) - 1.0f) * 0.125f);
    while (8 * (g + 1) * (g + 1) + 2 * (g + 1) <= bid) g++;
    while (8 * g * g + 2 * g > bid) g--;
    const int i = bid - (8 * g * g + 2 * g);    // [0, 16g+10)
    int rt, c;
    if (i < 16 * g + 4) { rt = i >> 2; c = i & 3; }
    else {
        const int r2 = i - (16 * g + 4);        // 0..5
        const int ra[6] = {1, 1, 1, 2, 2, 3};
        const int ca[6] = {1, 2, 3, 2, 3, 3};
        rt = 4 * g + ra[r2]; c = ca[r2];
    }
    const int ct = 4 * g + c;
    const bool isDiag = (rt == ct);
    const int rowBase = rt * BM;
    const int colBase = ct * BM;

    const int t    = threadIdx.x;
    const int lane = t & 63;
    const int wave = t >> 6;
    const int wr   = wave >> 1;           // wave row quadrant (0/1)
    const int wc   = wave & 1;            // wave col quadrant (0/1)
    const int quad = lane >> 4;           // 0..3
    const int l15  = lane & 15;

    __shared__ __align__(16) unsigned char Asmem[BM * BKB];   // 16 KB
    __shared__ __align__(16) unsigned char Bsmem[BM * BKB];   // 16 KB

    // staging lane map: per call a wave stages 8 rows (1 KB). lane i ->
    // row (i>>3) within the 8-row segment, LDS slot i&7; global chunk
    // (i&7)^((i>>3)&7) so that stored slot == chunk ^ (row&7).
    const int grow = lane >> 3;                              // 0..7
    const int gcol = ((lane & 7) ^ grow) * 16;               // swizzled chunk
    const unsigned char* gA = reps + (size_t)(rowBase + wave * 8 + grow) * D_DIM + gcol;
    const unsigned char* gB = reps + (size_t)(colBase + wave * 8 + grow) * D_DIM + gcol;
    unsigned char* lA = Asmem + wave * 8 * BKB;              // call j adds j*32*BKB
    unsigned char* lB = Bsmem + wave * 8 * BKB;

    // fragment read offsets: m-frag row ra = wr*64 + m*16 + l15; lane reads
    // logical chunks {2*quad, 2*quad+1} (k = quad*32..+32) at slots
    // chunk^(ra&7) -> base off + (off^16).
    int aoff[4], boff[4];
    #pragma unroll
    for (int m = 0; m < 4; m++) {
        const int ra = wr * 64 + m * 16 + l15;
        const int rb = wc * 64 + m * 16 + l15;
        aoff[m] = ra * BKB + ((2 * quad) ^ (ra & 7)) * 16;
        boff[m] = rb * BKB + ((2 * quad) ^ (rb & 7)) * 16;
    }

    f32x4 acc[4][4];
    #pragma unroll
    for (int mi = 0; mi < 4; mi++)
        #pragma unroll
        for (int ni = 0; ni < 4; ni++)
            acc[mi][ni] = (f32x4){0.f, 0.f, 0.f, 0.f};

    for (int kb = 0; kb < D_DIM; kb += BKB) {   // 8 iters
        __syncthreads();   // prev iter's ds_reads done before overwrite
        #pragma unroll
        for (int j = 0; j < 4; j++) {           // 4 calls x 32 rows each tile
            load_lds16(gA + kb + j * 32 * D_DIM, lA + j * 32 * BKB);
            load_lds16(gB + kb + j * 32 * D_DIM, lB + j * 32 * BKB);
        }
        __syncthreads();   // drains vmcnt (compiler-inserted waitcnt)

        i32x8 af[4], bf[4];
        #pragma unroll
        for (int m = 0; m < 4; m++) {
            const int4 alo = *(const int4*)(Asmem + aoff[m]);
            const int4 ahi = *(const int4*)(Asmem + (aoff[m] ^ 16));
            af[m] = (i32x8){alo.x, alo.y, alo.z, alo.w, ahi.x, ahi.y, ahi.z, ahi.w};
            const int4 blo = *(const int4*)(Bsmem + boff[m]);
            const int4 bhi = *(const int4*)(Bsmem + (boff[m] ^ 16));
            bf[m] = (i32x8){blo.x, blo.y, blo.z, blo.w, bhi.x, bhi.y, bhi.z, bhi.w};
        }

        #pragma unroll
        for (int mi = 0; mi < 4; mi++)
            #pragma unroll
            for (int ni = 0; ni < 4; ni++)
                acc[mi][ni] = __builtin_amdgcn_mfma_scale_f32_16x16x128_f8f6f4(
                    af[mi], bf[ni], acc[mi][ni],
                    0, 0,          // cbsz=0 (fp8 e4m3 A), blgp=0 (fp8 e4m3 B)
                    0, 127,        // scale A: opsel 0, e8m0 127 = 1.0
                    0, 127);       // scale B: unit
    }

    // Epilogue. C layout: col = lane&15, row = quad*4 + reg (shape-determined).
    // sim computed on 16x-scaled fp8 -> exp factor 2/256.
    float csum[4] = {0.f, 0.f, 0.f, 0.f};
    #pragma unroll
    for (int mi = 0; mi < 4; mi++) {
        const int rowA = rowBase + wr * 64 + mi * 16 + quad * 4;
        float prow[4] = {0.f, 0.f, 0.f, 0.f};
        #pragma unroll
        for (int ni = 0; ni < 4; ni++) {
            const int col = colBase + wc * 64 + ni * 16 + l15;
            const f32x4 a = acc[mi][ni];
            #pragma unroll
            for (int r = 0; r < 4; r++) {
                float e = __expf(a[r] * EXP_SCALE);
                if (isDiag && rowA + r == col) e = 0.0f;   // self-sim mask
                csum[ni] += e;
                prow[r]  += e;
            }
        }
        if (!isDiag) {
            #pragma unroll
            for (int r = 0; r < 4; r++) {   // row sums -> mirror tile
                float v = prow[r];
                v += __shfl_xor(v, 1);
                v += __shfl_xor(v, 2);
                v += __shfl_xor(v, 4);
                v += __shfl_xor(v, 8);
                if (l15 == 0) atomicAdd(denom + rowA + r, v);
            }
        }
    }
    #pragma unroll
    for (int ni = 0; ni < 4; ni++) {        // column sums across 4 quads
        float v = csum[ni];
        v += __shfl_xor(v, 16);
        v += __shfl_xor(v, 32);
        if (quad == 0)
            atomicAdd(denom + colBase + wc * 64 + ni * 16 + l15, v);
    }

    // ---- fence-free fused loss (see header comment) ----
    asm volatile("s_waitcnt vmcnt(0)" ::: "memory");   // issue-order only
    __shared__ int lastFlag;
    if (t == 0) {
        const int v = __hip_atomic_fetch_add(counter, 1, __ATOMIC_RELAXED,
                                             __HIP_MEMORY_SCOPE_AGENT);
        lastFlag = (v == GRID_SIM - 1);
    }
    __syncthreads();
    if (lastFlag) {
        if (t == 0)
            __hip_atomic_store(counter, 0, __ATOMIC_RELAXED,
                               __HIP_MEMORY_SCOPE_AGENT);   // next-replay reset
        float s = 0.f;
        for (int i2 = t; i2 < N_ROWS; i2 += 256) {
            const float d = __hip_atomic_load(denom + i2, __ATOMIC_RELAXED,
                                              __HIP_MEMORY_SCOPE_AGENT);
            const float p = pos[i2 & (B_ROWS - 1)];
            s += logf(d) - p * 2.0f;      // TEMP_INV, pos is unscaled fp32
        }
        #pragma unroll
        for (int off = 32; off >= 1; off >>= 1) s += __shfl_xor(s, off);
        __shared__ float red[4];
        if ((t & 63) == 0) red[t >> 6] = s;
        __syncthreads();
        if (t == 0) out[0] = (red[0] + red[1] + red[2] + red[3]) / (float)N_ROWS;
    }
}

// ---------------------------------------------------------------------------
extern "C" void kernel_launch(void* const* d_in, const int* in_sizes, int n_in,
                              void* d_out, int out_size, void* d_ws, size_t ws_size,
                              hipStream_t stream) {
    const float* emb_i = (const float*)d_in[0];
    const float* emb_j = (const float*)d_in[1];

    unsigned char* reps = (unsigned char*)d_ws;                       // 8 MB fp8 [8192][1024]
    float* pos   = (float*)((char*)d_ws + (size_t)N_ROWS * D_DIM);    // 16 KB
    float* denom = pos + B_ROWS;                                      // 32 KB
    int*   counter = (int*)(denom + N_ROWS);                          // 4 B ticket
    float* out   = (float*)d_out;

    normalize_kernel<<<B_ROWS, 256, 0, stream>>>(emb_i, emb_j, reps, pos, denom, counter);
    sim_denom_kernel<<<GRID_SIM, 256, 0, stream>>>(reps, denom, pos, out, counter);
}

// Round 10
// 127.143 us; speedup vs baseline: 1.1241x; 1.1241x over previous
//
#include <hip/hip_runtime.h>
#include <hip/hip_bf16.h>

// Problem constants (B=4096, D=1024 per reference setup_inputs)
#define B_ROWS 4096
#define D_DIM  1024          // elements == bytes in fp8
#define N_ROWS 8192          // 2B
// values scaled by 16 before fp8 cast -> sim scaled by 256; exp arg factor:
#define EXP_SCALE 0.0078125f // TEMP_INV / 256 = 2/256
#define FP8_SCALE 16.0f

#define NTILE 64
#define GRID_SIM 2080        // upper-triangle tiles incl. diagonal (8 x 260)

typedef __attribute__((ext_vector_type(4))) float f32x4;   // MFMA C/D frag
typedef __attribute__((ext_vector_type(8))) int   i32x8;   // MX MFMA A/B frag

// Async global->LDS DMA, 16 B per lane. LDS dest is WAVE-UNIFORM base;
// lane i's 16 B land at base + i*16 (per-lane global addr is free-form).
__device__ inline void load_lds16(const unsigned char* g, unsigned char* l) {
    __builtin_amdgcn_global_load_lds(
        (const __attribute__((address_space(1))) unsigned int*)g,
        (__attribute__((address_space(3))) unsigned int*)l,
        16, 0, 0);
}

// ---------------------------------------------------------------------------
// Kernel 1 (R13 form, proven): block-per-row L2 normalize -> fp8 e4m3 reps
// (x16 scale), [8192] rows x 1024 B. 4096 blocks x 256 thr; thread t owns
// elements 4t..4t+3 of row b in BOTH emb_i and emb_j. Coalesced 16 B/lane
// loads, butterfly + LDS cross-wave reduce, 4 B/lane fp8 stores.
// pos[b] = z_i(b).z_j(b) in fp32 (exact). Zeroes denom (blocks 0..31).
// ---------------------------------------------------------------------------
__global__ __launch_bounds__(256)
void normalize_kernel(const float* __restrict__ emb_i,
                      const float* __restrict__ emb_j,
                      unsigned char* __restrict__ reps,
                      float* __restrict__ pos,
                      float* __restrict__ denom) {
    const int b    = blockIdx.x;                     // 0..4095 (one row pair)
    const int t    = threadIdx.x;                    // 0..255
    const int lane = t & 63;
    const int wave = t >> 6;

    if (b < N_ROWS / 256) denom[b * 256 + t] = 0.0f;

    const float4 vi = ((const float4*)(emb_i + (size_t)b * D_DIM))[t];
    const float4 vj = ((const float4*)(emb_j + (size_t)b * D_DIM))[t];

    float si = vi.x*vi.x + vi.y*vi.y + vi.z*vi.z + vi.w*vi.w;
    float sj = vj.x*vj.x + vj.y*vj.y + vj.z*vj.z + vj.w*vj.w;
    float sd = vi.x*vj.x + vi.y*vj.y + vi.z*vj.z + vi.w*vj.w;

    #pragma unroll
    for (int off = 32; off >= 1; off >>= 1) {   // butterfly within wave
        si += __shfl_xor(si, off);
        sj += __shfl_xor(sj, off);
        sd += __shfl_xor(sd, off);
    }
    __shared__ float red[3][4];
    if (lane == 0) { red[0][wave] = si; red[1][wave] = sj; red[2][wave] = sd; }
    __syncthreads();
    si = red[0][0] + red[0][1] + red[0][2] + red[0][3];
    sj = red[1][0] + red[1][1] + red[1][2] + red[1][3];
    sd = red[2][0] + red[2][1] + red[2][2] + red[2][3];

    const float inv_i = FP8_SCALE / fmaxf(sqrtf(si), 1e-12f);
    const float inv_j = FP8_SCALE / fmaxf(sqrtf(sj), 1e-12f);
    if (t == 0) pos[b] = sd * (inv_i * inv_j) * (1.0f / (FP8_SCALE * FP8_SCALE));

    int a  = __builtin_amdgcn_cvt_pk_fp8_f32(vi.x * inv_i, vi.y * inv_i, 0, false);
    unsigned int ui = __builtin_amdgcn_cvt_pk_fp8_f32(vi.z * inv_i, vi.w * inv_i, a, true);
    int c  = __builtin_amdgcn_cvt_pk_fp8_f32(vj.x * inv_j, vj.y * inv_j, 0, false);
    unsigned int uj = __builtin_amdgcn_cvt_pk_fp8_f32(vj.z * inv_j, vj.w * inv_j, c, true);

    ((unsigned int*)(reps + (size_t)b * D_DIM))[t]            = ui;
    ((unsigned int*)(reps + (size_t)(b + B_ROWS) * D_DIM))[t] = uj;
}

// ---------------------------------------------------------------------------
// Kernel 2 (R18): EXACT R8/R13 K-loop (57.5 us fingerprint, (256,3),
// VGPR 84 + 64 AGPR acc). ONE change: XCD-aware tile swizzle (T1).
//
// WHY: FETCH_SIZE 77 MB = 9.6x reps (8 MB) — heavy panel re-fetch from
// beyond L2. Grouped enumeration gives consecutive tiles panel locality,
// but round-robin dispatch (XCD = bid % 8) scatters consecutive tiles
// across 8 XCDs, so every 4-MB XCD L2 pulls every panel. Remap
// ltid = (bid%8)*260 + bid/8 (bijective: 2080 = 8*260) so each XCD owns
// 260 CONSECUTIVE logical tiles (~26 groups sharing row/col panels).
//
// RETIRED LEVERS: deeper pipelines (R9-R12), occupancy 4/CU (R14 spill),
// loss fusion in any form (R15 fence poison, R17 fence-free still -14us).
// Do not restructure the K-loop; do not re-fuse.
//
// LDS: 128-B rows; 16-B chunk c of row r at slot c ^ (r&7). Fragment
// reads: per frag two ds_read_b128 at off, off^16. A and B use the same
// lane->k map, so the k-permutation cancels in the dot product; C/D layout
// is shape-determined (col=lane&15, row=quad*4+reg).
// ---------------------------------------------------------------------------
#define BM 128
#define BKB 128              // K-bytes (== elements) staged per iter

__global__ __launch_bounds__(256, 3)
void sim_denom_kernel(const unsigned char* __restrict__ reps,
                      float* __restrict__ denom) {
    // ---- XCD-aware swizzle: physical bid -> logical tile id ----
    const int bid = (blockIdx.x & 7) * (GRID_SIM / 8) + (blockIdx.x >> 3);

    // ---- tile decode: bid -> (rt, ct), rt <= ct (grouped enumeration) ----
    int g = (int)((__builtin_sqrtf(1.0f + 8.0f * (float)bid) - 1.0f) * 0.125f);
    while (8 * (g + 1) * (g + 1) + 2 * (g + 1) <= bid) g++;
    while (8 * g * g + 2 * g > bid) g--;
    const int i = bid - (8 * g * g + 2 * g);    // [0, 16g+10)
    int rt, c;
    if (i < 16 * g + 4) { rt = i >> 2; c = i & 3; }
    else {
        const int r2 = i - (16 * g + 4);        // 0..5
        const int ra[6] = {1, 1, 1, 2, 2, 3};
        const int ca[6] = {1, 2, 3, 2, 3, 3};
        rt = 4 * g + ra[r2]; c = ca[r2];
    }
    const int ct = 4 * g + c;
    const bool isDiag = (rt == ct);
    const int rowBase = rt * BM;
    const int colBase = ct * BM;

    const int t    = threadIdx.x;
    const int lane = t & 63;
    const int wave = t >> 6;
    const int wr   = wave >> 1;           // wave row quadrant (0/1)
    const int wc   = wave & 1;            // wave col quadrant (0/1)
    const int quad = lane >> 4;           // 0..3
    const int l15  = lane & 15;

    __shared__ __align__(16) unsigned char Asmem[BM * BKB];   // 16 KB
    __shared__ __align__(16) unsigned char Bsmem[BM * BKB];   // 16 KB

    // staging lane map: per call a wave stages 8 rows (1 KB). lane i ->
    // row (i>>3) within the 8-row segment, LDS slot i&7; global chunk
    // (i&7)^((i>>3)&7) so that stored slot == chunk ^ (row&7).
    const int grow = lane >> 3;                              // 0..7
    const int gcol = ((lane & 7) ^ grow) * 16;               // swizzled chunk
    const unsigned char* gA = reps + (size_t)(rowBase + wave * 8 + grow) * D_DIM + gcol;
    const unsigned char* gB = reps + (size_t)(colBase + wave * 8 + grow) * D_DIM + gcol;
    unsigned char* lA = Asmem + wave * 8 * BKB;              // call j adds j*32*BKB
    unsigned char* lB = Bsmem + wave * 8 * BKB;

    // fragment read offsets: m-frag row ra = wr*64 + m*16 + l15; lane reads
    // logical chunks {2*quad, 2*quad+1} (k = quad*32..+32) at slots
    // chunk^(ra&7) -> base off + (off^16).
    int aoff[4], boff[4];
    #pragma unroll
    for (int m = 0; m < 4; m++) {
        const int ra = wr * 64 + m * 16 + l15;
        const int rb = wc * 64 + m * 16 + l15;
        aoff[m] = ra * BKB + ((2 * quad) ^ (ra & 7)) * 16;
        boff[m] = rb * BKB + ((2 * quad) ^ (rb & 7)) * 16;
    }

    f32x4 acc[4][4];
    #pragma unroll
    for (int mi = 0; mi < 4; mi++)
        #pragma unroll
        for (int ni = 0; ni < 4; ni++)
            acc[mi][ni] = (f32x4){0.f, 0.f, 0.f, 0.f};

    for (int kb = 0; kb < D_DIM; kb += BKB) {   // 8 iters
        __syncthreads();   // prev iter's ds_reads done before overwrite
        #pragma unroll
        for (int j = 0; j < 4; j++) {           // 4 calls x 32 rows each tile
            load_lds16(gA + kb + j * 32 * D_DIM, lA + j * 32 * BKB);
            load_lds16(gB + kb + j * 32 * D_DIM, lB + j * 32 * BKB);
        }
        __syncthreads();   // drains vmcnt (compiler-inserted waitcnt)

        i32x8 af[4], bf[4];
        #pragma unroll
        for (int m = 0; m < 4; m++) {
            const int4 alo = *(const int4*)(Asmem + aoff[m]);
            const int4 ahi = *(const int4*)(Asmem + (aoff[m] ^ 16));
            af[m] = (i32x8){alo.x, alo.y, alo.z, alo.w, ahi.x, ahi.y, ahi.z, ahi.w};
            const int4 blo = *(const int4*)(Bsmem + boff[m]);
            const int4 bhi = *(const int4*)(Bsmem + (boff[m] ^ 16));
            bf[m] = (i32x8){blo.x, blo.y, blo.z, blo.w, bhi.x, bhi.y, bhi.z, bhi.w};
        }

        #pragma unroll
        for (int mi = 0; mi < 4; mi++)
            #pragma unroll
            for (int ni = 0; ni < 4; ni++)
                acc[mi][ni] = __builtin_amdgcn_mfma_scale_f32_16x16x128_f8f6f4(
                    af[mi], bf[ni], acc[mi][ni],
                    0, 0,          // cbsz=0 (fp8 e4m3 A), blgp=0 (fp8 e4m3 B)
                    0, 127,        // scale A: opsel 0, e8m0 127 = 1.0
                    0, 127);       // scale B: unit
    }

    // Epilogue. C layout: col = lane&15, row = quad*4 + reg (shape-determined).
    // sim computed on 16x-scaled fp8 -> exp factor 2/256.
    float csum[4] = {0.f, 0.f, 0.f, 0.f};
    #pragma unroll
    for (int mi = 0; mi < 4; mi++) {
        const int rowA = rowBase + wr * 64 + mi * 16 + quad * 4;
        float prow[4] = {0.f, 0.f, 0.f, 0.f};
        #pragma unroll
        for (int ni = 0; ni < 4; ni++) {
            const int col = colBase + wc * 64 + ni * 16 + l15;
            const f32x4 a = acc[mi][ni];
            #pragma unroll
            for (int r = 0; r < 4; r++) {
                float e = __expf(a[r] * EXP_SCALE);
                if (isDiag && rowA + r == col) e = 0.0f;   // self-sim mask
                csum[ni] += e;
                prow[r]  += e;
            }
        }
        if (!isDiag) {
            #pragma unroll
            for (int r = 0; r < 4; r++) {   // row sums -> mirror tile
                float v = prow[r];
                v += __shfl_xor(v, 1);
                v += __shfl_xor(v, 2);
                v += __shfl_xor(v, 4);
                v += __shfl_xor(v, 8);
                if (l15 == 0) atomicAdd(denom + rowA + r, v);
            }
        }
    }
    #pragma unroll
    for (int ni = 0; ni < 4; ni++) {        // column sums across 4 quads
        float v = csum[ni];
        v += __shfl_xor(v, 16);
        v += __shfl_xor(v, 32);
        if (quad == 0)
            atomicAdd(denom + colBase + wc * 64 + ni * 16 + l15, v);
    }
}

// ---------------------------------------------------------------------------
// Kernel 3: loss = mean over 2B rows of (log(denom) - pos/T). Single block,
// 1024 threads (8 loop iters).
// ---------------------------------------------------------------------------
__global__ __launch_bounds__(1024)
void loss_kernel(const float* __restrict__ denom,
                 const float* __restrict__ pos,
                 float* __restrict__ out) {
    const int t = threadIdx.x;
    float s = 0.f;
    for (int i = t; i < N_ROWS; i += 1024) {
        const float p = pos[i & (B_ROWS - 1)];
        s += logf(denom[i]) - p * 2.0f;     // TEMP_INV, pos is unscaled fp32
    }
    #pragma unroll
    for (int off = 32; off >= 1; off >>= 1) s += __shfl_xor(s, off);
    __shared__ float red[16];
    if ((t & 63) == 0) red[t >> 6] = s;
    __syncthreads();
    if (t == 0) {
        float tot = 0.f;
        #pragma unroll
        for (int w = 0; w < 16; w++) tot += red[w];
        out[0] = tot / (float)N_ROWS;
    }
}

// ---------------------------------------------------------------------------
extern "C" void kernel_launch(void* const* d_in, const int* in_sizes, int n_in,
                              void* d_out, int out_size, void* d_ws, size_t ws_size,
                              hipStream_t stream) {
    const float* emb_i = (const float*)d_in[0];
    const float* emb_j = (const float*)d_in[1];

    unsigned char* reps = (unsigned char*)d_ws;                       // 8 MB fp8 [8192][1024]
    float* pos   = (float*)((char*)d_ws + (size_t)N_ROWS * D_DIM);    // 16 KB
    float* denom = pos + B_ROWS;                                      // 32 KB
    float* out   = (float*)d_out;

    normalize_kernel<<<B_ROWS, 256, 0, stream>>>(emb_i, emb_j, reps, pos, denom);
    sim_denom_kernel<<<GRID_SIM, 256, 0, stream>>>(reps, denom);
    loss_kernel<<<1, 1024, 0, stream>>>(denom, pos, out);
}